// Round 15
// baseline (361.555 us; speedup 1.0000x reference)
//
#include <hip/hip_runtime.h>
#include <hip/hip_bf16.h>
#include <hip/hip_fp16.h>
#include <math.h>

#define N_NODES 50000
#define N_EDGES 800000
#define ET (N_EDGES + N_NODES)
#define HTOT 400
#define SENTINEL 50000u

#define SCAN_CHUNK 1024
#define NSCB ((N_NODES + SCAN_CHUNK - 1) / SCAN_CHUNK)   // 49

typedef __attribute__((ext_vector_type(4))) float f32x4;
typedef __attribute__((ext_vector_type(8))) short bf16x8;

static const int INS_h[4] = {16, 80, 144, 272};
static const int K32_h[4] = {32, 96, 160, 288};
static const int HO_h[4]  = {64, 64, 128, 128};

#define LOG2E_F 1.4426950408889634f

// ---- fused prep: copy_x + deg zero + weight concats + av sentinel + packed attn weights ----

struct PrepArgs {
    const float* x; __hip_bfloat16* h; int* deg;
    const float* Ws0; const float* Wl0;
    const float* Ws1; const float* Wl1;
    const float* Ws2; const float* Wl2;
    const float* Ws3; const float* Wl3;
    const float* Wm1;
    __hip_bfloat16* Wt0; __hip_bfloat16* Wt1; __hip_bfloat16* Wt2;
    __hip_bfloat16* Wt3; __hip_bfloat16* WtF;
    ushort* av;
    const float* Wp0; const float* bp0;
    const float* Wp1; const float* bp1;
    const float* Wp2; const float* bp2;
    const float* Wp3; const float* bp3;
    uint* wph0; uint* wph1; uint* wph2; uint* wph3;
};

__device__ inline void concat1(const float* __restrict__ W0, const float* __restrict__ W1,
                               int K, int K32, int fo, __hip_bfloat16* __restrict__ Wt, int i) {
    int c = i / K32, kk = i - c * K32;
    float v = 0.f;
    if (kk < K) v = (c < fo) ? W0[kk * fo + c] : W1[kk * fo + (c - fo)];
    Wt[i] = __float2bfloat16(v);
}

#define PREP_TOTAL 1008848

__global__ __launch_bounds__(256) void prep_kernel(PrepArgs a) {
    int i = blockIdx.x * 256 + threadIdx.x;
    if (i < 800000) {
        int n = i >> 4, c = i & 15;
        a.h[n * HTOT + c] = __float2bfloat16(a.x[i]);
        return;
    }
    i -= 800000;
    if (i < 50000) { a.deg[i] = 0; return; }
    i -= 50000;
    if (i < 4096)  { concat1(a.Ws0, a.Wl0, 16, 32, 64, a.Wt0, i); return; }
    i -= 4096;
    if (i < 12288) { concat1(a.Ws1, a.Wl1, 80, 96, 64, a.Wt1, i); return; }
    i -= 12288;
    if (i < 40960) { concat1(a.Ws2, a.Wl2, 144, 160, 128, a.Wt2, i); return; }
    i -= 40960;
    if (i < 73728) { concat1(a.Ws3, a.Wl3, 272, 288, 128, a.Wt3, i); return; }
    i -= 73728;
    if (i < 26624) {
        int c = i / 416, kk = i - c * 416;
        float v = (kk < 400) ? a.Wm1[kk * 64 + c] : 0.f;
        a.WtF[i] = __float2bfloat16(v);
        return;
    }
    i -= 26624;
    if (i < 384) {
        // sentinel rows: a = -inf (0xFC00), v = 0, for both layouts
        if (i < 128) a.av[50000 * 128 + i] = (i < 64)  ? 0xFC00 : 0;   // fo=64 layout
        else { int j = i - 128; a.av[50000 * 256 + j] = (j < 128) ? 0xFC00 : 0; } // fo=128
        return;
    }
    i -= 384;
    if (i < 768) {
        // packed attn weights: per layer, arrays [wp0|wp1|wp2|bp], half2 per pair
        const float* Wp; const float* bpp; uint* dst; int fo; int q = i;
        if (q < 128)      { Wp = a.Wp0; bpp = a.bp0; dst = a.wph0; fo = 64; }
        else if (q < 256) { q -= 128; Wp = a.Wp1; bpp = a.bp1; dst = a.wph1; fo = 64; }
        else if (q < 512) { q -= 256; Wp = a.Wp2; bpp = a.bp2; dst = a.wph2; fo = 128; }
        else              { q -= 512; Wp = a.Wp3; bpp = a.bp3; dst = a.wph3; fo = 128; }
        int hf = fo >> 1;
        int arr = q / hf, pr = q - arr * hf;
        int c = 2 * pr;
        float v0, v1;
        if (arr < 3) { v0 = Wp[arr * fo + c]; v1 = Wp[arr * fo + c + 1]; }
        else         { v0 = bpp[c]; v1 = bpp[c + 1]; }
        __half2 hh = __floats2half2_rn(v0, v1);
        dst[q] = *reinterpret_cast<uint*>(&hh);
    }
}

// ---------------- CSR build ----------------

__global__ void hist_kernel(const int* __restrict__ ei, int* __restrict__ deg) {
    int e = blockIdx.x * blockDim.x + threadIdx.x;
    if (e >= ET) return;
    int dst = (e < N_EDGES) ? ei[N_EDGES + e] : (e - N_EDGES);
    atomicAdd(&deg[dst], 1);
}

__global__ __launch_bounds__(256) void scan_p1(const int* __restrict__ deg,
                                               int* __restrict__ bsum) {
    __shared__ int red[256];
    const int b = blockIdx.x, t = threadIdx.x;
    const int base = b * SCAN_CHUNK + t * 4;
    int s = 0;
#pragma unroll
    for (int j = 0; j < 4; ++j) {
        int i = base + j;
        if (i < N_NODES) s += deg[i];
    }
    red[t] = s;
    __syncthreads();
    for (int off = 128; off > 0; off >>= 1) {
        if (t < off) red[t] += red[t + off];
        __syncthreads();
    }
    if (t == 0) bsum[b] = red[0];
}

// p3 with p2 folded in: each block redundantly wave-scans the 49 block sums.
__global__ __launch_bounds__(256) void scan_p3(const int* __restrict__ deg,
                                               const int* __restrict__ bsum,
                                               int* __restrict__ row_ptr,
                                               int* __restrict__ cursor) {
    __shared__ int ts[256];
    __shared__ int sb[2];
    const int b = blockIdx.x, t = threadIdx.x;
    if (t < 64) {
        int v = (t < NSCB) ? bsum[t] : 0;
        int inc = v;
#pragma unroll
        for (int off = 1; off < 64; off <<= 1) {
            int u = __shfl_up(inc, off);
            if (t >= off) inc += u;
        }
        if (t == b) sb[0] = inc - v;
        if (t == 63) sb[1] = inc;
    }
    const int base = b * SCAN_CHUNK + t * 4;
    int v[4];
    int s = 0;
#pragma unroll
    for (int j = 0; j < 4; ++j) {
        int i = base + j;
        v[j] = (i < N_NODES) ? deg[i] : 0;
        s += v[j];
    }
    ts[t] = s;
    __syncthreads();
    for (int off = 1; off < 256; off <<= 1) {
        int u = (t >= off) ? ts[t - off] : 0;
        __syncthreads();
        ts[t] += u;
        __syncthreads();
    }
    int excl = sb[0] + ts[t] - s;
#pragma unroll
    for (int j = 0; j < 4; ++j) {
        int i = base + j;
        if (i < N_NODES) {
            row_ptr[i] = excl;
            cursor[i] = excl;
            excl += v[j];
        }
    }
    if (b == 0 && t == 0) row_ptr[N_NODES] = sb[1];
}

// edata entry (8 B): x = src(16b) | dz_fp16(16b) ; y = half2(dx, dy)
__global__ void scatter_kernel(const int* __restrict__ ei, const float* __restrict__ x,
                               int* __restrict__ cursor, uint2* __restrict__ edata) {
    int e = blockIdx.x * blockDim.x + threadIdx.x;
    if (e >= ET) return;
    int src, dst;
    if (e < N_EDGES) { src = ei[e]; dst = ei[N_EDGES + e]; }
    else             { src = dst = e - N_EDGES; }
    int p = atomicAdd(&cursor[dst], 1);
    float4 pd = *(const float4*)&x[dst * 16];
    float4 ps = *(const float4*)&x[src * 16];
    __half dxh = __float2half(pd.x - ps.x);
    __half dyh = __float2half(pd.y - ps.y);
    __half dzh = __float2half(pd.z - ps.z);
    uint w0 = (uint)src | ((uint)__half_as_ushort(dzh) << 16);
    __half2 xy;
    xy.x = dxh; xy.y = dyh;
    edata[p] = make_uint2(w0, *(uint*)&xy);
}

// ---------------- bf16 MFMA GEMM; LDS-staged vectorized fp16 epilogue ----------------

template <bool FUSE>
__global__ __launch_bounds__(256) void gemm3_kernel(
    const __hip_bfloat16* __restrict__ A, int lda,
    const __hip_bfloat16* __restrict__ Wt, int K32,
    const float* __restrict__ bias,
    __half* __restrict__ av, int fo,
    int M, int K, int GXP,
    const float* __restrict__ W2, const float* __restrict__ b2,
    float* __restrict__ out) {
    __shared__ float smemf[9728];
    ushort* sA = (ushort*)smemf;
    ushort* sB = (ushort*)smemf + 10240;
    const int t = threadIdx.x;
    const int bid = blockIdx.x;
    const int gxp = bid % GXP;
    const int gy = bid / GXP;
    const int r0 = gxp * 128, c0 = gy * 64;
    const int w = t >> 6, lane = t & 63;
    const int l15 = lane & 15, l4 = lane >> 4;

    f32x4 acc[2][4];
#pragma unroll
    for (int i = 0; i < 2; ++i)
#pragma unroll
        for (int j = 0; j < 4; ++j) acc[i][j] = (f32x4){0.f, 0.f, 0.f, 0.f};

    const int sr = t >> 2, sq = (t & 3) * 8;
    const int ar1 = min(r0 + sr, M - 1), ar2 = min(r0 + sr + 64, M - 1);
    const size_t a1b = (size_t)ar1 * lda, a2b = (size_t)ar2 * lda;
    const size_t wb = (size_t)(c0 + sr) * K32;
    const int nk = K32 >> 5;

    uint4 ga0, ga1, gb;
    const uint4 z4 = {0u, 0u, 0u, 0u};
    {
        const int kk = sq;
        const bool ok = kk < K;
        ga0 = ok ? *(const uint4*)(A + a1b + kk) : z4;
        ga1 = ok ? *(const uint4*)(A + a2b + kk) : z4;
        gb  = *(const uint4*)(Wt + wb + kk);
        *(uint4*)(sA + sr * 40 + sq) = ga0;
        *(uint4*)(sA + (sr + 64) * 40 + sq) = ga1;
        *(uint4*)(sB + sr * 40 + sq) = gb;
    }
    __syncthreads();

    int buf = 0;
    for (int kc = 0; kc < nk; ++kc) {
        const bool nx = (kc + 1) < nk;
        if (nx) {
            const int kk = (kc + 1) * 32 + sq;
            const bool ok = kk < K;
            ga0 = ok ? *(const uint4*)(A + a1b + kk) : z4;
            ga1 = ok ? *(const uint4*)(A + a2b + kk) : z4;
            gb  = *(const uint4*)(Wt + wb + kk);
        }
        const ushort* bA = sA + buf * 5120 + w * 1280;
        const ushort* bB = sB + buf * 2560;
        bf16x8 af[2], bfr[4];
#pragma unroll
        for (int i = 0; i < 2; ++i)
            af[i] = *(const bf16x8*)(bA + (i * 16 + l15) * 40 + l4 * 8);
#pragma unroll
        for (int j = 0; j < 4; ++j)
            bfr[j] = *(const bf16x8*)(bB + (j * 16 + l15) * 40 + l4 * 8);
#pragma unroll
        for (int i = 0; i < 2; ++i)
#pragma unroll
            for (int j = 0; j < 4; ++j)
                acc[i][j] = __builtin_amdgcn_mfma_f32_16x16x32_bf16(af[i], bfr[j], acc[i][j], 0, 0, 0);
        if (nx) {
            const int ob = buf ^ 1;
            *(uint4*)(sA + ob * 5120 + sr * 40 + sq) = ga0;
            *(uint4*)(sA + ob * 5120 + (sr + 64) * 40 + sq) = ga1;
            *(uint4*)(sB + ob * 2560 + sr * 40 + sq) = gb;
        }
        __syncthreads();
        buf ^= 1;
    }

    if (!FUSE) {
        const int n2 = 2 * fo;
        ushort* st = (ushort*)smemf;                 // [128][68] fp16 staging
#pragma unroll
        for (int i = 0; i < 2; ++i)
#pragma unroll
            for (int j = 0; j < 4; ++j)
#pragma unroll
                for (int p = 0; p < 4; ++p) {
                    int lrow = w * 32 + i * 16 + l4 * 4 + p;
                    int col = c0 + j * 16 + l15;
                    float vv = acc[i][j][p];
                    if (col < fo) vv *= -LOG2E_F;    // a-slot prescaled for exp2
                    __half hv = __float2half(vv);
                    st[lrow * 68 + j * 16 + l15] = __half_as_ushort(hv);
                }
        __syncthreads();
        const int row = t >> 1, seg = (t & 1) * 32;
        const int grow = r0 + row;
        if (grow < M) {
            __half* dst = av + (size_t)grow * n2 + c0 + seg;
#pragma unroll
            for (int u = 0; u < 4; ++u) {
                uint2 qa = *(const uint2*)(st + row * 68 + seg + 8 * u);
                uint2 qb = *(const uint2*)(st + row * 68 + seg + 8 * u + 4);
                uint4 q4 = make_uint4(qa.x, qa.y, qb.x, qb.y);
                *(uint4*)(dst + 8 * u) = q4;
            }
        }
    } else {
#pragma unroll
        for (int i = 0; i < 2; ++i)
#pragma unroll
            for (int j = 0; j < 4; ++j)
#pragma unroll
                for (int p = 0; p < 4; ++p) {
                    int lrow = w * 32 + i * 16 + l4 * 4 + p;
                    int col = j * 16 + l15;
                    smemf[lrow * 68 + col] = acc[i][j][p] + bias[col];
                }
        smemf[8704 + t] = W2[t];
        smemf[8704 + 256 + t] = W2[256 + t];
        __syncthreads();
        const int row = t >> 1, oc = (t & 1) * 4;
        f32x4 o = *(const f32x4*)&b2[oc];
#pragma unroll 8
        for (int k = 0; k < 64; ++k) {
            float a = smemf[row * 68 + k];
            o += a * *(const f32x4*)&smemf[8704 + k * 8 + oc];
        }
        const int grow = r0 + row;
        if (grow < M) *(f32x4*)&out[(size_t)grow * 8 + oc] = o;
    }
}

// ---------------- attention: r12 loop + sentinel redirect + packed fp16 weights ----------------
// av row: [0,fo) = -a_src*log2e (fp16), [fo,2fo) = v (fp16); row SENTINEL = (-inf, 0).
// p = exp2(delta*log2e - a_src*log2e); a_dst cancels in the per-dst softmax.
// Prefetch one iteration ahead (register copies — proven faster than ping-pong, r14);
// tail slots redirect src -> SENTINEL (one cndmask, p = 0 exactly).

__device__ inline __half2 h2e2(__half2 a) {
    __half2 r;
    r.x = hexp2(__low2half(a));
    r.y = hexp2(__high2half(a));
    return r;
}

template <int LPE>   // lanes per edge: 8 (fo=64) or 16 (fo=128); 8 channels per lane
__global__ __launch_bounds__(256) void attn_kernel(
    __hip_bfloat16* __restrict__ h,
    const __half* __restrict__ av,
    const uint* __restrict__ wph,
    const int* __restrict__ rowp, const uint2* __restrict__ edata,
    int colbase) {
    constexpr int FO = 8 * LPE;
    constexpr int SLOTS = 64 / LPE;
    const int wid = (blockIdx.x * (int)blockDim.x + (int)threadIdx.x) >> 6;
    if (wid >= N_NODES) return;
    const int lane = threadIdx.x & 63;
    const int e = lane / LPE, lp = lane % LPE;
    const int cb = lp * 8;

    uint4 w0 = *(const uint4*)(wph + 0 * (FO / 2) + lp * 4);
    uint4 w1 = *(const uint4*)(wph + 1 * (FO / 2) + lp * 4);
    uint4 w2 = *(const uint4*)(wph + 2 * (FO / 2) + lp * 4);
    uint4 wb4 = *(const uint4*)(wph + 3 * (FO / 2) + lp * 4);
    const __half2* wp0h = (const __half2*)&w0;
    const __half2* wp1h = (const __half2*)&w1;
    const __half2* wp2h = (const __half2*)&w2;
    const __half2* bph  = (const __half2*)&wb4;

    __half2 s2[4], n2v[4];
    const __half2 hz = __float2half2_rn(0.f);
#pragma unroll
    for (int j = 0; j < 4; ++j) { s2[j] = hz; n2v[j] = hz; }

    const uint* avu = (const uint*)av;
    const __half2 L2E = __float2half2_rn(LOG2E_F);
    const int beg = rowp[wid], end = rowp[wid + 1], last = end - 1;

    uint2 ed_c, ed_n;
    uint4 a_c, v_c, a_n, v_n;
    auto ld = [&](int b, uint2& ed, uint4& a4, uint4& v4) {
        ed = edata[min(b + e, last)];
        const uint src = (b + e < end) ? (ed.x & 0xFFFFu) : SENTINEL;
        const uint* rb = avu + (size_t)src * FO + (cb >> 1);
        a4 = *(const uint4*)rb;
        v4 = *(const uint4*)(rb + FO / 2);
    };
    auto compute = [&](const uint2& ed, const uint4& a4, const uint4& v4) {
        __half2 dz2 = __half2half2(__ushort_as_half((ushort)(ed.x >> 16)));
        __half2 dxy = *(const __half2*)&ed.y;
        __half2 dx2 = __half2half2(__low2half(dxy));
        __half2 dy2 = __half2half2(__high2half(dxy));
        const uint* ap = (const uint*)&a4;
        const uint* vp = (const uint*)&v4;
#pragma unroll
        for (int jj = 0; jj < 4; ++jj) {
            __half2 d  = __hfma2(dx2, wp0h[jj], __hfma2(dy2, wp1h[jj], __hfma2(dz2, wp2h[jj], bph[jj])));
            __half2 a2 = __hfma2(d, L2E, *(const __half2*)&ap[jj]);
            __half2 vd = __hadd2(*(const __half2*)&vp[jj], d);
            __half2 p2 = h2e2(a2);
            s2[jj] = __hadd2(s2[jj], p2);
            n2v[jj] = __hfma2(p2, vd, n2v[jj]);
        }
    };

    ld(beg, ed_c, a_c, v_c);
    for (int base = beg; base < end; base += SLOTS) {
        ld(base + SLOTS, ed_n, a_n, v_n);
        compute(ed_c, a_c, v_c);
        ed_c = ed_n; a_c = a_n; v_c = v_n;
    }

    // convert slot accumulators to fp32, then cross-slot reduce
    float s[8], num[8];
#pragma unroll
    for (int jj = 0; jj < 4; ++jj) {
        s[2 * jj]       = __half2float(__low2half(s2[jj]));
        s[2 * jj + 1]   = __half2float(__high2half(s2[jj]));
        num[2 * jj]     = __half2float(__low2half(n2v[jj]));
        num[2 * jj + 1] = __half2float(__high2half(n2v[jj]));
    }
#pragma unroll
    for (int j = 0; j < 8; ++j) {
#pragma unroll
        for (int off = LPE; off < 64; off <<= 1) {
            s[j] += __shfl_xor(s[j], off);
            num[j] += __shfl_xor(num[j], off);
        }
    }
    if (e == 0) {
        ushort o[8];
#pragma unroll
        for (int j = 0; j < 8; ++j) {
            float xi = num[j] / s[j];
            xi = xi > 0.f ? xi : 0.01f * xi;
            __hip_bfloat16 b = __float2bfloat16(xi);
            o[j] = *(ushort*)&b;
        }
        ushort* dst = (ushort*)&h[(size_t)wid * HTOT + colbase + cb];
        *(uint4*)dst = *(uint4*)o;
    }
}

// ---------------- launch ----------------

extern "C" void kernel_launch(void* const* d_in, const int* in_sizes, int n_in,
                              void* d_out, int out_size, void* d_ws, size_t ws_size,
                              hipStream_t stream) {
    const float* x = (const float*)d_in[0];
    const int* ei = (const int*)d_in[1];
    const float *Wl[4], *Ws[4], *Wp[4], *bp[4];
    for (int i = 0; i < 4; ++i) {
        Wl[i] = (const float*)d_in[2 + 5 * i];
        Ws[i] = (const float*)d_in[3 + 5 * i];
        Wp[i] = (const float*)d_in[5 + 5 * i];
        bp[i] = (const float*)d_in[6 + 5 * i];
    }
    const float* Wm1 = (const float*)d_in[22];
    const float* bm1 = (const float*)d_in[23];
    const float* Wm2 = (const float*)d_in[24];
    const float* bm2 = (const float*)d_in[25];
    float* out = (float*)d_out;

    char* ws = (char*)d_ws;
    size_t off = 0;
    auto alloc = [&](size_t bytes) -> void* {
        void* p = ws + off;
        off += (bytes + 255) & ~(size_t)255;
        return p;
    };
    __hip_bfloat16* h = (__hip_bfloat16*)alloc((size_t)N_NODES * HTOT * 2);
    __half* av = (__half*)alloc((size_t)(N_NODES + 1) * 256 * 2);   // +1 sentinel row
    __hip_bfloat16* Wt0 = (__hip_bfloat16*)alloc((size_t)4096 * 2);
    __hip_bfloat16* Wt1 = (__hip_bfloat16*)alloc((size_t)12288 * 2);
    __hip_bfloat16* Wt2 = (__hip_bfloat16*)alloc((size_t)40960 * 2);
    __hip_bfloat16* Wt3 = (__hip_bfloat16*)alloc((size_t)73728 * 2);
    __hip_bfloat16* WtF = (__hip_bfloat16*)alloc((size_t)26624 * 2);
    uint* wph0 = (uint*)alloc((size_t)128 * 4);
    uint* wph1 = (uint*)alloc((size_t)128 * 4);
    uint* wph2 = (uint*)alloc((size_t)256 * 4);
    uint* wph3 = (uint*)alloc((size_t)256 * 4);
    int* deg = (int*)alloc((size_t)N_NODES * 4);
    int* rowp = (int*)alloc((size_t)(N_NODES + 1) * 4);
    int* cursor = (int*)alloc((size_t)N_NODES * 4);
    int* bsum = (int*)alloc((size_t)(NSCB + 1) * 4);
    uint2* edata = (uint2*)alloc((size_t)ET * 8);
    (void)ws_size; (void)n_in; (void)in_sizes; (void)out_size;

    PrepArgs pa;
    pa.x = x; pa.h = h; pa.deg = deg;
    pa.Ws0 = Ws[0]; pa.Wl0 = Wl[0];
    pa.Ws1 = Ws[1]; pa.Wl1 = Wl[1];
    pa.Ws2 = Ws[2]; pa.Wl2 = Wl[2];
    pa.Ws3 = Ws[3]; pa.Wl3 = Wl[3];
    pa.Wm1 = Wm1;
    pa.Wt0 = Wt0; pa.Wt1 = Wt1; pa.Wt2 = Wt2; pa.Wt3 = Wt3; pa.WtF = WtF;
    pa.av = (ushort*)av;
    pa.Wp0 = Wp[0]; pa.bp0 = bp[0];
    pa.Wp1 = Wp[1]; pa.bp1 = bp[1];
    pa.Wp2 = Wp[2]; pa.bp2 = bp[2];
    pa.Wp3 = Wp[3]; pa.bp3 = bp[3];
    pa.wph0 = wph0; pa.wph1 = wph1; pa.wph2 = wph2; pa.wph3 = wph3;
    prep_kernel<<<(PREP_TOTAL + 255) / 256, 256, 0, stream>>>(pa);

    hist_kernel<<<(ET + 255) / 256, 256, 0, stream>>>(ei, deg);
    scan_p1<<<NSCB, 256, 0, stream>>>(deg, bsum);
    scan_p3<<<NSCB, 256, 0, stream>>>(deg, bsum, rowp, cursor);
    scatter_kernel<<<(ET + 255) / 256, 256, 0, stream>>>(ei, x, cursor, edata);

    const int M = N_NODES;
    const int GXP = (((M + 127) / 128 + 7) / 8) * 8;     // 392, multiple of 8
    const int nbn = (N_NODES + 3) / 4;
    __hip_bfloat16* Wts[4] = {Wt0, Wt1, Wt2, Wt3};
    uint* wphs[4] = {wph0, wph1, wph2, wph3};
    for (int L = 0; L < 4; ++L) {
        const int K = INS_h[L], K32 = K32_h[L], fo = HO_h[L], n2 = 2 * fo;
        gemm3_kernel<false><<<GXP * (n2 / 64), 256, 0, stream>>>(
            h, HTOT, Wts[L], K32, nullptr, av, fo, M, K, GXP, nullptr, nullptr, nullptr);
        if (fo == 64)
            attn_kernel<8><<<nbn, 256, 0, stream>>>(h, av, wphs[L], rowp, edata, K);
        else
            attn_kernel<16><<<nbn, 256, 0, stream>>>(h, av, wphs[L], rowp, edata, K);
    }
    gemm3_kernel<true><<<GXP, 256, 0, stream>>>(h, HTOT, WtF, 416, bm1,
                                                nullptr, 0, M, 400, GXP, Wm2, bm2, out);
}

// Round 16
// 349.768 us; speedup vs baseline: 1.0337x; 1.0337x over previous
//
#include <hip/hip_runtime.h>
#include <hip/hip_bf16.h>
#include <hip/hip_fp16.h>
#include <math.h>

#define N_NODES 50000
#define N_EDGES 800000
#define ET (N_EDGES + N_NODES)
#define HTOT 400
#define SENTINEL 50000u

#define SCAN_CHUNK 1024
#define NSCB ((N_NODES + SCAN_CHUNK - 1) / SCAN_CHUNK)   // 49

typedef __attribute__((ext_vector_type(4))) float f32x4;
typedef __attribute__((ext_vector_type(8))) short bf16x8;

static const int INS_h[4] = {16, 80, 144, 272};
static const int K32_h[4] = {32, 96, 160, 288};
static const int HO_h[4]  = {64, 64, 128, 128};

#define LOG2E_F 1.4426950408889634f

// ---- fused prep: copy_x + deg zero + weight concats + av sentinel + packed attn weights ----

struct PrepArgs {
    const float* x; __hip_bfloat16* h; int* deg;
    const float* Ws0; const float* Wl0;
    const float* Ws1; const float* Wl1;
    const float* Ws2; const float* Wl2;
    const float* Ws3; const float* Wl3;
    const float* Wm1;
    __hip_bfloat16* Wt0; __hip_bfloat16* Wt1; __hip_bfloat16* Wt2;
    __hip_bfloat16* Wt3; __hip_bfloat16* WtF;
    ushort* av;
    const float* Wp0; const float* bp0;
    const float* Wp1; const float* bp1;
    const float* Wp2; const float* bp2;
    const float* Wp3; const float* bp3;
    uint* wph0; uint* wph1; uint* wph2; uint* wph3;
};

__device__ inline void concat1(const float* __restrict__ W0, const float* __restrict__ W1,
                               int K, int K32, int fo, __hip_bfloat16* __restrict__ Wt, int i) {
    int c = i / K32, kk = i - c * K32;
    float v = 0.f;
    if (kk < K) v = (c < fo) ? W0[kk * fo + c] : W1[kk * fo + (c - fo)];
    Wt[i] = __float2bfloat16(v);
}

#define PREP_TOTAL 1008848

__global__ __launch_bounds__(256) void prep_kernel(PrepArgs a) {
    int i = blockIdx.x * 256 + threadIdx.x;
    if (i < 800000) {
        int n = i >> 4, c = i & 15;
        a.h[n * HTOT + c] = __float2bfloat16(a.x[i]);
        return;
    }
    i -= 800000;
    if (i < 50000) { a.deg[i] = 0; return; }
    i -= 50000;
    if (i < 4096)  { concat1(a.Ws0, a.Wl0, 16, 32, 64, a.Wt0, i); return; }
    i -= 4096;
    if (i < 12288) { concat1(a.Ws1, a.Wl1, 80, 96, 64, a.Wt1, i); return; }
    i -= 12288;
    if (i < 40960) { concat1(a.Ws2, a.Wl2, 144, 160, 128, a.Wt2, i); return; }
    i -= 40960;
    if (i < 73728) { concat1(a.Ws3, a.Wl3, 272, 288, 128, a.Wt3, i); return; }
    i -= 73728;
    if (i < 26624) {
        int c = i / 416, kk = i - c * 416;
        float v = (kk < 400) ? a.Wm1[kk * 64 + c] : 0.f;
        a.WtF[i] = __float2bfloat16(v);
        return;
    }
    i -= 26624;
    if (i < 384) {
        // sentinel rows: a = -inf (0xFC00), v = 0, for both layouts
        if (i < 128) a.av[50000 * 128 + i] = (i < 64)  ? 0xFC00 : 0;   // fo=64 layout
        else { int j = i - 128; a.av[50000 * 256 + j] = (j < 128) ? 0xFC00 : 0; } // fo=128
        return;
    }
    i -= 384;
    if (i < 768) {
        // packed attn weights: per layer, arrays [wp0|wp1|wp2|bp], half2 per pair
        const float* Wp; const float* bpp; uint* dst; int fo; int q = i;
        if (q < 128)      { Wp = a.Wp0; bpp = a.bp0; dst = a.wph0; fo = 64; }
        else if (q < 256) { q -= 128; Wp = a.Wp1; bpp = a.bp1; dst = a.wph1; fo = 64; }
        else if (q < 512) { q -= 256; Wp = a.Wp2; bpp = a.bp2; dst = a.wph2; fo = 128; }
        else              { q -= 512; Wp = a.Wp3; bpp = a.bp3; dst = a.wph3; fo = 128; }
        int hf = fo >> 1;
        int arr = q / hf, pr = q - arr * hf;
        int c = 2 * pr;
        float v0, v1;
        if (arr < 3) { v0 = Wp[arr * fo + c]; v1 = Wp[arr * fo + c + 1]; }
        else         { v0 = bpp[c]; v1 = bpp[c + 1]; }
        __half2 hh = __floats2half2_rn(v0, v1);
        dst[q] = *reinterpret_cast<uint*>(&hh);
    }
}

// ---------------- CSR build ----------------

__global__ void hist_kernel(const int* __restrict__ ei, int* __restrict__ deg) {
    int e = blockIdx.x * blockDim.x + threadIdx.x;
    if (e >= ET) return;
    int dst = (e < N_EDGES) ? ei[N_EDGES + e] : (e - N_EDGES);
    atomicAdd(&deg[dst], 1);
}

__global__ __launch_bounds__(256) void scan_p1(const int* __restrict__ deg,
                                               int* __restrict__ bsum) {
    __shared__ int red[256];
    const int b = blockIdx.x, t = threadIdx.x;
    const int base = b * SCAN_CHUNK + t * 4;
    int s = 0;
#pragma unroll
    for (int j = 0; j < 4; ++j) {
        int i = base + j;
        if (i < N_NODES) s += deg[i];
    }
    red[t] = s;
    __syncthreads();
    for (int off = 128; off > 0; off >>= 1) {
        if (t < off) red[t] += red[t + off];
        __syncthreads();
    }
    if (t == 0) bsum[b] = red[0];
}

// p3 with p2 folded in: each block redundantly wave-scans the 49 block sums.
__global__ __launch_bounds__(256) void scan_p3(const int* __restrict__ deg,
                                               const int* __restrict__ bsum,
                                               int* __restrict__ row_ptr,
                                               int* __restrict__ cursor) {
    __shared__ int ts[256];
    __shared__ int sb[2];
    const int b = blockIdx.x, t = threadIdx.x;
    if (t < 64) {
        int v = (t < NSCB) ? bsum[t] : 0;
        int inc = v;
#pragma unroll
        for (int off = 1; off < 64; off <<= 1) {
            int u = __shfl_up(inc, off);
            if (t >= off) inc += u;
        }
        if (t == b) sb[0] = inc - v;
        if (t == 63) sb[1] = inc;
    }
    const int base = b * SCAN_CHUNK + t * 4;
    int v[4];
    int s = 0;
#pragma unroll
    for (int j = 0; j < 4; ++j) {
        int i = base + j;
        v[j] = (i < N_NODES) ? deg[i] : 0;
        s += v[j];
    }
    ts[t] = s;
    __syncthreads();
    for (int off = 1; off < 256; off <<= 1) {
        int u = (t >= off) ? ts[t - off] : 0;
        __syncthreads();
        ts[t] += u;
        __syncthreads();
    }
    int excl = sb[0] + ts[t] - s;
#pragma unroll
    for (int j = 0; j < 4; ++j) {
        int i = base + j;
        if (i < N_NODES) {
            row_ptr[i] = excl;
            cursor[i] = excl;
            excl += v[j];
        }
    }
    if (b == 0 && t == 0) row_ptr[N_NODES] = sb[1];
}

// edata entry (8 B): x = src(16b) | dz_fp16(16b) ; y = half2(dx, dy)
__global__ void scatter_kernel(const int* __restrict__ ei, const float* __restrict__ x,
                               int* __restrict__ cursor, uint2* __restrict__ edata) {
    int e = blockIdx.x * blockDim.x + threadIdx.x;
    if (e >= ET) return;
    int src, dst;
    if (e < N_EDGES) { src = ei[e]; dst = ei[N_EDGES + e]; }
    else             { src = dst = e - N_EDGES; }
    int p = atomicAdd(&cursor[dst], 1);
    float4 pd = *(const float4*)&x[dst * 16];
    float4 ps = *(const float4*)&x[src * 16];
    __half dxh = __float2half(pd.x - ps.x);
    __half dyh = __float2half(pd.y - ps.y);
    __half dzh = __float2half(pd.z - ps.z);
    uint w0 = (uint)src | ((uint)__half_as_ushort(dzh) << 16);
    __half2 xy;
    xy.x = dxh; xy.y = dyh;
    edata[p] = make_uint2(w0, *(uint*)&xy);
}

// ---------------- bf16 MFMA GEMM; direct per-element fp16 epilogue (r12-proven) ----------------

template <bool FUSE>
__global__ __launch_bounds__(256) void gemm3_kernel(
    const __hip_bfloat16* __restrict__ A, int lda,
    const __hip_bfloat16* __restrict__ Wt, int K32,
    const float* __restrict__ bias,
    __half* __restrict__ av, int fo,
    int M, int K, int GXP,
    const float* __restrict__ W2, const float* __restrict__ b2,
    float* __restrict__ out) {
    __shared__ float smemf[9728];
    ushort* sA = (ushort*)smemf;
    ushort* sB = (ushort*)smemf + 10240;
    const int t = threadIdx.x;
    const int bid = blockIdx.x;
    const int gxp = bid % GXP;
    const int gy = bid / GXP;
    const int r0 = gxp * 128, c0 = gy * 64;
    const int w = t >> 6, lane = t & 63;
    const int l15 = lane & 15, l4 = lane >> 4;

    f32x4 acc[2][4];
#pragma unroll
    for (int i = 0; i < 2; ++i)
#pragma unroll
        for (int j = 0; j < 4; ++j) acc[i][j] = (f32x4){0.f, 0.f, 0.f, 0.f};

    const int sr = t >> 2, sq = (t & 3) * 8;
    const int ar1 = min(r0 + sr, M - 1), ar2 = min(r0 + sr + 64, M - 1);
    const size_t a1b = (size_t)ar1 * lda, a2b = (size_t)ar2 * lda;
    const size_t wb = (size_t)(c0 + sr) * K32;
    const int nk = K32 >> 5;

    uint4 ga0, ga1, gb;
    const uint4 z4 = {0u, 0u, 0u, 0u};
    {
        const int kk = sq;
        const bool ok = kk < K;
        ga0 = ok ? *(const uint4*)(A + a1b + kk) : z4;
        ga1 = ok ? *(const uint4*)(A + a2b + kk) : z4;
        gb  = *(const uint4*)(Wt + wb + kk);
        *(uint4*)(sA + sr * 40 + sq) = ga0;
        *(uint4*)(sA + (sr + 64) * 40 + sq) = ga1;
        *(uint4*)(sB + sr * 40 + sq) = gb;
    }
    __syncthreads();

    int buf = 0;
    for (int kc = 0; kc < nk; ++kc) {
        const bool nx = (kc + 1) < nk;
        if (nx) {
            const int kk = (kc + 1) * 32 + sq;
            const bool ok = kk < K;
            ga0 = ok ? *(const uint4*)(A + a1b + kk) : z4;
            ga1 = ok ? *(const uint4*)(A + a2b + kk) : z4;
            gb  = *(const uint4*)(Wt + wb + kk);
        }
        const ushort* bA = sA + buf * 5120 + w * 1280;
        const ushort* bB = sB + buf * 2560;
        bf16x8 af[2], bfr[4];
#pragma unroll
        for (int i = 0; i < 2; ++i)
            af[i] = *(const bf16x8*)(bA + (i * 16 + l15) * 40 + l4 * 8);
#pragma unroll
        for (int j = 0; j < 4; ++j)
            bfr[j] = *(const bf16x8*)(bB + (j * 16 + l15) * 40 + l4 * 8);
#pragma unroll
        for (int i = 0; i < 2; ++i)
#pragma unroll
            for (int j = 0; j < 4; ++j)
                acc[i][j] = __builtin_amdgcn_mfma_f32_16x16x32_bf16(af[i], bfr[j], acc[i][j], 0, 0, 0);
        if (nx) {
            const int ob = buf ^ 1;
            *(uint4*)(sA + ob * 5120 + sr * 40 + sq) = ga0;
            *(uint4*)(sA + ob * 5120 + (sr + 64) * 40 + sq) = ga1;
            *(uint4*)(sB + ob * 2560 + sr * 40 + sq) = gb;
        }
        __syncthreads();
        buf ^= 1;
    }

    if (!FUSE) {
        const int n2 = 2 * fo;
#pragma unroll
        for (int i = 0; i < 2; ++i)
#pragma unroll
            for (int j = 0; j < 4; ++j)
#pragma unroll
                for (int p = 0; p < 4; ++p) {
                    int row = r0 + w * 32 + i * 16 + l4 * 4 + p;
                    int col = c0 + j * 16 + l15;
                    if (row < M) {
                        float vv = acc[i][j][p];
                        if (col < fo) vv *= -LOG2E_F;    // a-slot prescaled for exp2
                        av[(size_t)row * n2 + col] = __float2half(vv);
                    }
                }
    } else {
#pragma unroll
        for (int i = 0; i < 2; ++i)
#pragma unroll
            for (int j = 0; j < 4; ++j)
#pragma unroll
                for (int p = 0; p < 4; ++p) {
                    int lrow = w * 32 + i * 16 + l4 * 4 + p;
                    int col = j * 16 + l15;
                    smemf[lrow * 68 + col] = acc[i][j][p] + bias[col];
                }
        smemf[8704 + t] = W2[t];
        smemf[8704 + 256 + t] = W2[256 + t];
        __syncthreads();
        const int row = t >> 1, oc = (t & 1) * 4;
        f32x4 o = *(const f32x4*)&b2[oc];
#pragma unroll 8
        for (int k = 0; k < 64; ++k) {
            float a = smemf[row * 68 + k];
            o += a * *(const f32x4*)&smemf[8704 + k * 8 + oc];
        }
        const int grow = r0 + row;
        if (grow < M) *(f32x4*)&out[(size_t)grow * 8 + oc] = o;
    }
}

// ---------------- attention: r12 loop + sentinel redirect + packed fp16 weights ----------------
// av row: [0,fo) = -a_src*log2e (fp16), [fo,2fo) = v (fp16); row SENTINEL = (-inf, 0).
// p = exp2(delta*log2e - a_src*log2e); a_dst cancels in the per-dst softmax.
// Prefetch one iteration ahead (register copies — proven best, r13/r14 A/B);
// tail slots redirect src -> SENTINEL (one cndmask, p = 0 exactly).

__device__ inline __half2 h2e2(__half2 a) {
    __half2 r;
    r.x = hexp2(__low2half(a));
    r.y = hexp2(__high2half(a));
    return r;
}

template <int LPE>   // lanes per edge: 8 (fo=64) or 16 (fo=128); 8 channels per lane
__global__ __launch_bounds__(256) void attn_kernel(
    __hip_bfloat16* __restrict__ h,
    const __half* __restrict__ av,
    const uint* __restrict__ wph,
    const int* __restrict__ rowp, const uint2* __restrict__ edata,
    int colbase) {
    constexpr int FO = 8 * LPE;
    constexpr int SLOTS = 64 / LPE;
    const int wid = (blockIdx.x * (int)blockDim.x + (int)threadIdx.x) >> 6;
    if (wid >= N_NODES) return;
    const int lane = threadIdx.x & 63;
    const int e = lane / LPE, lp = lane % LPE;
    const int cb = lp * 8;

    uint4 w0 = *(const uint4*)(wph + 0 * (FO / 2) + lp * 4);
    uint4 w1 = *(const uint4*)(wph + 1 * (FO / 2) + lp * 4);
    uint4 w2 = *(const uint4*)(wph + 2 * (FO / 2) + lp * 4);
    uint4 wb4 = *(const uint4*)(wph + 3 * (FO / 2) + lp * 4);
    const __half2* wp0h = (const __half2*)&w0;
    const __half2* wp1h = (const __half2*)&w1;
    const __half2* wp2h = (const __half2*)&w2;
    const __half2* bph  = (const __half2*)&wb4;

    __half2 s2[4], n2v[4];
    const __half2 hz = __float2half2_rn(0.f);
#pragma unroll
    for (int j = 0; j < 4; ++j) { s2[j] = hz; n2v[j] = hz; }

    const uint* avu = (const uint*)av;
    const __half2 L2E = __float2half2_rn(LOG2E_F);
    const int beg = rowp[wid], end = rowp[wid + 1], last = end - 1;

    uint2 ed_c, ed_n;
    uint4 a_c, v_c, a_n, v_n;
    auto ld = [&](int b, uint2& ed, uint4& a4, uint4& v4) {
        ed = edata[min(b + e, last)];
        const uint src = (b + e < end) ? (ed.x & 0xFFFFu) : SENTINEL;
        const uint* rb = avu + (size_t)src * FO + (cb >> 1);
        a4 = *(const uint4*)rb;
        v4 = *(const uint4*)(rb + FO / 2);
    };
    auto compute = [&](const uint2& ed, const uint4& a4, const uint4& v4) {
        __half2 dz2 = __half2half2(__ushort_as_half((ushort)(ed.x >> 16)));
        __half2 dxy = *(const __half2*)&ed.y;
        __half2 dx2 = __half2half2(__low2half(dxy));
        __half2 dy2 = __half2half2(__high2half(dxy));
        const uint* ap = (const uint*)&a4;
        const uint* vp = (const uint*)&v4;
#pragma unroll
        for (int jj = 0; jj < 4; ++jj) {
            __half2 d  = __hfma2(dx2, wp0h[jj], __hfma2(dy2, wp1h[jj], __hfma2(dz2, wp2h[jj], bph[jj])));
            __half2 a2 = __hfma2(d, L2E, *(const __half2*)&ap[jj]);
            __half2 vd = __hadd2(*(const __half2*)&vp[jj], d);
            __half2 p2 = h2e2(a2);
            s2[jj] = __hadd2(s2[jj], p2);
            n2v[jj] = __hfma2(p2, vd, n2v[jj]);
        }
    };

    ld(beg, ed_c, a_c, v_c);
    for (int base = beg; base < end; base += SLOTS) {
        ld(base + SLOTS, ed_n, a_n, v_n);
        compute(ed_c, a_c, v_c);
        ed_c = ed_n; a_c = a_n; v_c = v_n;
    }

    // convert slot accumulators to fp32, then cross-slot reduce
    float s[8], num[8];
#pragma unroll
    for (int jj = 0; jj < 4; ++jj) {
        s[2 * jj]       = __half2float(__low2half(s2[jj]));
        s[2 * jj + 1]   = __half2float(__high2half(s2[jj]));
        num[2 * jj]     = __half2float(__low2half(n2v[jj]));
        num[2 * jj + 1] = __half2float(__high2half(n2v[jj]));
    }
#pragma unroll
    for (int j = 0; j < 8; ++j) {
#pragma unroll
        for (int off = LPE; off < 64; off <<= 1) {
            s[j] += __shfl_xor(s[j], off);
            num[j] += __shfl_xor(num[j], off);
        }
    }
    if (e == 0) {
        ushort o[8];
#pragma unroll
        for (int j = 0; j < 8; ++j) {
            float xi = num[j] / s[j];
            xi = xi > 0.f ? xi : 0.01f * xi;
            __hip_bfloat16 b = __float2bfloat16(xi);
            o[j] = *(ushort*)&b;
        }
        ushort* dst = (ushort*)&h[(size_t)wid * HTOT + colbase + cb];
        *(uint4*)dst = *(uint4*)o;
    }
}

// ---------------- launch ----------------

extern "C" void kernel_launch(void* const* d_in, const int* in_sizes, int n_in,
                              void* d_out, int out_size, void* d_ws, size_t ws_size,
                              hipStream_t stream) {
    const float* x = (const float*)d_in[0];
    const int* ei = (const int*)d_in[1];
    const float *Wl[4], *Ws[4], *Wp[4], *bp[4];
    for (int i = 0; i < 4; ++i) {
        Wl[i] = (const float*)d_in[2 + 5 * i];
        Ws[i] = (const float*)d_in[3 + 5 * i];
        Wp[i] = (const float*)d_in[5 + 5 * i];
        bp[i] = (const float*)d_in[6 + 5 * i];
    }
    const float* Wm1 = (const float*)d_in[22];
    const float* bm1 = (const float*)d_in[23];
    const float* Wm2 = (const float*)d_in[24];
    const float* bm2 = (const float*)d_in[25];
    float* out = (float*)d_out;

    char* ws = (char*)d_ws;
    size_t off = 0;
    auto alloc = [&](size_t bytes) -> void* {
        void* p = ws + off;
        off += (bytes + 255) & ~(size_t)255;
        return p;
    };
    __hip_bfloat16* h = (__hip_bfloat16*)alloc((size_t)N_NODES * HTOT * 2);
    __half* av = (__half*)alloc((size_t)(N_NODES + 1) * 256 * 2);   // +1 sentinel row
    __hip_bfloat16* Wt0 = (__hip_bfloat16*)alloc((size_t)4096 * 2);
    __hip_bfloat16* Wt1 = (__hip_bfloat16*)alloc((size_t)12288 * 2);
    __hip_bfloat16* Wt2 = (__hip_bfloat16*)alloc((size_t)40960 * 2);
    __hip_bfloat16* Wt3 = (__hip_bfloat16*)alloc((size_t)73728 * 2);
    __hip_bfloat16* WtF = (__hip_bfloat16*)alloc((size_t)26624 * 2);
    uint* wph0 = (uint*)alloc((size_t)128 * 4);
    uint* wph1 = (uint*)alloc((size_t)128 * 4);
    uint* wph2 = (uint*)alloc((size_t)256 * 4);
    uint* wph3 = (uint*)alloc((size_t)256 * 4);
    int* deg = (int*)alloc((size_t)N_NODES * 4);
    int* rowp = (int*)alloc((size_t)(N_NODES + 1) * 4);
    int* cursor = (int*)alloc((size_t)N_NODES * 4);
    int* bsum = (int*)alloc((size_t)(NSCB + 1) * 4);
    uint2* edata = (uint2*)alloc((size_t)ET * 8);
    (void)ws_size; (void)n_in; (void)in_sizes; (void)out_size;

    PrepArgs pa;
    pa.x = x; pa.h = h; pa.deg = deg;
    pa.Ws0 = Ws[0]; pa.Wl0 = Wl[0];
    pa.Ws1 = Ws[1]; pa.Wl1 = Wl[1];
    pa.Ws2 = Ws[2]; pa.Wl2 = Wl[2];
    pa.Ws3 = Ws[3]; pa.Wl3 = Wl[3];
    pa.Wm1 = Wm1;
    pa.Wt0 = Wt0; pa.Wt1 = Wt1; pa.Wt2 = Wt2; pa.Wt3 = Wt3; pa.WtF = WtF;
    pa.av = (ushort*)av;
    pa.Wp0 = Wp[0]; pa.bp0 = bp[0];
    pa.Wp1 = Wp[1]; pa.bp1 = bp[1];
    pa.Wp2 = Wp[2]; pa.bp2 = bp[2];
    pa.Wp3 = Wp[3]; pa.bp3 = bp[3];
    pa.wph0 = wph0; pa.wph1 = wph1; pa.wph2 = wph2; pa.wph3 = wph3;
    prep_kernel<<<(PREP_TOTAL + 255) / 256, 256, 0, stream>>>(pa);

    hist_kernel<<<(ET + 255) / 256, 256, 0, stream>>>(ei, deg);
    scan_p1<<<NSCB, 256, 0, stream>>>(deg, bsum);
    scan_p3<<<NSCB, 256, 0, stream>>>(deg, bsum, rowp, cursor);
    scatter_kernel<<<(ET + 255) / 256, 256, 0, stream>>>(ei, x, cursor, edata);

    const int M = N_NODES;
    const int GXP = (((M + 127) / 128 + 7) / 8) * 8;     // 392, multiple of 8
    const int nbn = (N_NODES + 3) / 4;
    __hip_bfloat16* Wts[4] = {Wt0, Wt1, Wt2, Wt3};
    uint* wphs[4] = {wph0, wph1, wph2, wph3};
    for (int L = 0; L < 4; ++L) {
        const int K = INS_h[L], K32 = K32_h[L], fo = HO_h[L], n2 = 2 * fo;
        gemm3_kernel<false><<<GXP * (n2 / 64), 256, 0, stream>>>(
            h, HTOT, Wts[L], K32, nullptr, av, fo, M, K, GXP, nullptr, nullptr, nullptr);
        if (fo == 64)
            attn_kernel<8><<<nbn, 256, 0, stream>>>(h, av, wphs[L], rowp, edata, K);
        else
            attn_kernel<16><<<nbn, 256, 0, stream>>>(h, av, wphs[L], rowp, edata, K);
    }
    gemm3_kernel<true><<<GXP, 256, 0, stream>>>(h, HTOT, WtF, 416, bm1,
                                                nullptr, 0, M, 400, GXP, Wm2, bm2, out);
}